// Round 1
// baseline (214.665 us; speedup 1.0000x reference)
//
#include <hip/hip_runtime.h>

#define S0 480
#define S1 360
#define S2 32
#define CH 32
#define EPS 1e-5f
#define SLOPE 0.01f

#define LOOKUP_INTS (2 * S0 * S1 * S2)          // 11,059,200
#define LOOKUP_BYTES ((size_t)LOOKUP_INTS * 4)  // 44,236,800

__global__ __launch_bounds__(256) void scatter_lookup_k(
    const int4* __restrict__ coords, int* __restrict__ lookup, int n)
{
    int i = blockIdx.x * 256 + threadIdx.x;
    if (i < n) {
        int4 c = coords[i];
        int lin = ((c.x * S0 + c.y) * S1 + c.z) * S2 + c.w;
        lookup[lin] = i;
    }
}

__global__ __launch_bounds__(256) void conv_leaky_stats_k(
    const float* __restrict__ features,
    const int4*  __restrict__ coords,
    const float* __restrict__ weight,
    const int*   __restrict__ lookup,
    float*       __restrict__ x_out,   // d_out reused as x storage
    float*       __restrict__ stats,   // [0..31]=sum, [32..63]=sumsq
    int n)
{
    int tid = threadIdx.x;
    int i = blockIdx.x * 256 + tid;
    bool active = (i < n);

    float acc[CH];
#pragma unroll
    for (int oc = 0; oc < CH; ++oc) acc[oc] = 0.f;

    int nbrs[9];
#pragma unroll
    for (int k = 0; k < 9; ++k) nbrs[k] = -1;

    if (active) {
        int4 c = coords[i];
        int lin = ((c.x * S0 + c.y) * S1 + c.z) * S2 + c.w;
#pragma unroll
        for (int kd0 = 0; kd0 < 3; ++kd0) {
            int n0 = c.y + kd0 - 1;
            bool v0 = (n0 >= 0) & (n0 < S0);
#pragma unroll
            for (int kd2 = 0; kd2 < 3; ++kd2) {
                int n2 = c.w + kd2 - 1;
                bool v = v0 & (n2 >= 0) & (n2 < S2);
                int l2 = lin + (kd0 - 1) * (S1 * S2) + (kd2 - 1);
                nbrs[kd0 * 3 + kd2] = v ? lookup[l2] : -1;
            }
        }
    }

#pragma unroll 1
    for (int k = 0; k < 9; ++k) {
        int nbr = nbrs[k];
        float row[CH];
        if (nbr >= 0) {
            const float4* fr = (const float4*)(features + (size_t)nbr * CH);
#pragma unroll
            for (int j = 0; j < 8; ++j) {
                float4 f4 = fr[j];
                row[4 * j + 0] = f4.x; row[4 * j + 1] = f4.y;
                row[4 * j + 2] = f4.z; row[4 * j + 3] = f4.w;
            }
        } else {
#pragma unroll
            for (int j = 0; j < CH; ++j) row[j] = 0.f;
        }
        const float* wk = weight + k * (CH * CH);   // uniform address -> s_load
#pragma unroll
        for (int ic = 0; ic < CH; ++ic) {
            float f = row[ic];
#pragma unroll
            for (int oc = 0; oc < CH; ++oc)
                acc[oc] = fmaf(f, wk[ic * CH + oc], acc[oc]);
        }
    }

    // LeakyReLU (inactive lanes have acc == 0, contribute 0 to stats)
#pragma unroll
    for (int oc = 0; oc < CH; ++oc)
        acc[oc] = acc[oc] >= 0.f ? acc[oc] : SLOPE * acc[oc];

    if (active) {
        float4* xo = (float4*)(x_out + (size_t)i * CH);
#pragma unroll
        for (int j = 0; j < 8; ++j)
            xo[j] = make_float4(acc[4 * j + 0], acc[4 * j + 1],
                                acc[4 * j + 2], acc[4 * j + 3]);
    }

    // ---- fused BN-stats: wave butterfly reduce -> LDS -> 32 atomics/block ----
    __shared__ float wsum[4][CH];
    __shared__ float wsq[4][CH];
    int wave = tid >> 6;
    int lane = tid & 63;
#pragma unroll
    for (int oc = 0; oc < CH; ++oc) {
        float s = acc[oc];
        float q = acc[oc] * acc[oc];
#pragma unroll
        for (int m = 32; m > 0; m >>= 1) {
            s += __shfl_xor(s, m, 64);
            q += __shfl_xor(q, m, 64);
        }
        if (lane == 0) { wsum[wave][oc] = s; wsq[wave][oc] = q; }
    }
    __syncthreads();
    if (tid < CH) {
        float s = wsum[0][tid] + wsum[1][tid] + wsum[2][tid] + wsum[3][tid];
        float q = wsq[0][tid] + wsq[1][tid] + wsq[2][tid] + wsq[3][tid];
        atomicAdd(&stats[tid], s);
        atomicAdd(&stats[CH + tid], q);
    }
}

__global__ __launch_bounds__(256) void bn_apply_k(
    float* __restrict__ x,              // in-place on d_out
    const float* __restrict__ stats,
    const float* __restrict__ gamma,
    const float* __restrict__ beta,
    int n)
{
    int total4 = n * (CH / 4);          // # of float4 (8 per row)
    int stride = gridDim.x * blockDim.x;           // multiple of 8
    int g = blockIdx.x * blockDim.x + threadIdx.x;
    int c4 = g & 7;                      // fixed float4-slot within row

    float scale[4], shift[4];
    float rn = 1.0f / (float)n;
#pragma unroll
    for (int j = 0; j < 4; ++j) {
        int oc = c4 * 4 + j;
        float m  = stats[oc] * rn;
        float v  = stats[CH + oc] * rn - m * m;
        float iv = rsqrtf(v + EPS) * gamma[oc];
        scale[j] = iv;
        shift[j] = beta[oc] - m * iv;
    }

    float4* x4 = (float4*)x;
    for (; g < total4; g += stride) {
        float4 v = x4[g];
        v.x = fmaf(v.x, scale[0], shift[0]);
        v.y = fmaf(v.y, scale[1], shift[1]);
        v.z = fmaf(v.z, scale[2], shift[2]);
        v.w = fmaf(v.w, scale[3], shift[3]);
        x4[g] = v;
    }
}

extern "C" void kernel_launch(void* const* d_in, const int* in_sizes, int n_in,
                              void* d_out, int out_size, void* d_ws, size_t ws_size,
                              hipStream_t stream)
{
    const float* features = (const float*)d_in[0];
    const int4*  coords   = (const int4*)d_in[1];
    const float* weight   = (const float*)d_in[2];
    const float* gamma    = (const float*)d_in[3];
    const float* beta     = (const float*)d_in[4];
    float* out = (float*)d_out;

    int n = in_sizes[0] / CH;            // 400000

    int*   lookup = (int*)d_ws;
    float* stats  = (float*)((char*)d_ws + LOOKUP_BYTES);

    hipMemsetAsync(lookup, 0xFF, LOOKUP_BYTES, stream);
    hipMemsetAsync(stats, 0, 2 * CH * sizeof(float), stream);

    int blocks = (n + 255) / 256;
    scatter_lookup_k<<<blocks, 256, 0, stream>>>(coords, lookup, n);

    conv_leaky_stats_k<<<blocks, 256, 0, stream>>>(
        features, coords, weight, lookup, out, stats, n);

    bn_apply_k<<<2048, 256, 0, stream>>>(out, stats, gamma, beta, n);
}

// Round 2
// 110.543 us; speedup vs baseline: 1.9419x; 1.9419x over previous
//
#include <hip/hip_runtime.h>

#define S0 480
#define S1 360
#define S2 32
#define CH 32
#define EPS 1e-5f
#define SLOPE 0.01f

#define LOOKUP_INTS (2 * S0 * S1 * S2)          // 11,059,200
#define LOOKUP_BYTES ((size_t)LOOKUP_INTS * 4)  // 44,236,800

typedef short short8 __attribute__((ext_vector_type(8)));
typedef float f32x16 __attribute__((ext_vector_type(16)));

__device__ __forceinline__ unsigned short f32_to_bf16_rne(float f) {
    union { float f; unsigned int u; } v; v.f = f;
    unsigned int x = v.u;
    unsigned int r = (x + 0x7FFFu + ((x >> 16) & 1u)) >> 16;
    return (unsigned short)r;
}

// ---- scatter lookup + convert features fp32 -> bf16 --------------------
__global__ __launch_bounds__(256) void scatter_convert_k(
    const float4* __restrict__ features,
    const int4*   __restrict__ coords,
    int*          __restrict__ lookup,
    unsigned short* __restrict__ featb,
    int n)
{
    int i = blockIdx.x * 256 + threadIdx.x;
    if (i >= n) return;
    int4 c = coords[i];
    int lin = ((c.x * S0 + c.y) * S1 + c.z) * S2 + c.w;
    lookup[lin] = i;

    const float4* fr = features + (size_t)i * 8;
    ushort4* fo = (ushort4*)(featb + (size_t)i * CH);
#pragma unroll
    for (int j = 0; j < 8; ++j) {
        float4 f = fr[j];
        ushort4 u;
        u.x = f32_to_bf16_rne(f.x);
        u.y = f32_to_bf16_rne(f.y);
        u.z = f32_to_bf16_rne(f.z);
        u.w = f32_to_bf16_rne(f.w);
        fo[j] = u;
    }
}

// ---- pre-pack weights into per-lane MFMA B fragments -------------------
// B layout for mfma_f32_32x32x16_bf16: col = lane&31, k = 8*(lane>>5)+j
// frag[t][h] covers ic = h*16 + 8*(lane>>5) + j, oc = lane&31
__global__ void bfrag_prep_k(const float* __restrict__ weight,
                             short8* __restrict__ bfrag)
{
    int lane = threadIdx.x;          // 64 threads
    int half = lane >> 5;
    int col  = lane & 31;
#pragma unroll
    for (int t = 0; t < 9; ++t)
#pragma unroll
        for (int h = 0; h < 2; ++h) {
            short8 fr;
#pragma unroll
            for (int j = 0; j < 8; ++j) {
                int ic = h * 16 + half * 8 + j;
                fr[j] = (short)f32_to_bf16_rne(weight[t * (CH * CH) + ic * CH + col]);
            }
            bfrag[(t * 2 + h) * 64 + lane] = fr;
        }
}

// ---- conv via MFMA: one wave = 32 points x 32 oc -----------------------
__global__ __launch_bounds__(256) void conv_mfma_k(
    const short*  __restrict__ featb,
    const int4*   __restrict__ coords,
    const int*    __restrict__ lookup,
    const short8* __restrict__ bfrag,
    float*        __restrict__ xout,
    float*        __restrict__ stats,
    int n, int ntile, int nwaves)
{
    int tid  = threadIdx.x;
    int lane = tid & 63;
    int wv   = tid >> 6;
    int half = lane >> 5;
    int col  = lane & 31;

    // weight fragments (registers, reused across tiles)
    short8 B[9][2];
#pragma unroll
    for (int t = 0; t < 9; ++t)
#pragma unroll
        for (int h = 0; h < 2; ++h)
            B[t][h] = bfrag[(t * 2 + h) * 64 + lane];

    float s = 0.f, q = 0.f;

    int gw = blockIdx.x * 4 + wv;
    for (int tile = gw; tile < ntile; tile += nwaves) {
        int p = tile * 32 + col;                  // this lane's point (row)
        int4 c = coords[p];
        int lin = ((c.x * S0 + c.y) * S1 + c.z) * S2 + c.w;
        int nbr[9];
#pragma unroll
        for (int d0 = 0; d0 < 3; ++d0) {
            int n0 = c.y + d0 - 1;
            bool v0 = (n0 >= 0) & (n0 < S0);
#pragma unroll
            for (int d2 = 0; d2 < 3; ++d2) {
                int n2 = c.w + d2 - 1;
                bool v = v0 & (n2 >= 0) & (n2 < S2);
                nbr[d0 * 3 + d2] = v ? lookup[lin + (d0 - 1) * (S1 * S2) + (d2 - 1)] : -1;
            }
        }

        f32x16 acc;
#pragma unroll
        for (int r = 0; r < 16; ++r) acc[r] = 0.f;

#pragma unroll
        for (int t = 0; t < 9; ++t) {
            int nb = nbr[t];
            short8 a0, a1;
            if (nb >= 0) {
                const short* fp = featb + (size_t)nb * CH;
                a0 = *(const short8*)(fp + half * 8);        // ic 0..15 slice
                a1 = *(const short8*)(fp + 16 + half * 8);   // ic 16..31 slice
            } else {
#pragma unroll
                for (int j = 0; j < 8; ++j) { a0[j] = 0; a1[j] = 0; }
            }
            acc = __builtin_amdgcn_mfma_f32_32x32x16_bf16(a0, B[t][0], acc, 0, 0, 0);
            acc = __builtin_amdgcn_mfma_f32_32x32x16_bf16(a1, B[t][1], acc, 0, 0, 0);
        }

        // LeakyReLU + store + local stats
        // C/D layout: col = lane&31, row = (r&3) + 8*(r>>2) + 4*half
        bool live = (p < n);
        float* xrow = xout + (size_t)tile * 32 * CH + col;
#pragma unroll
        for (int r = 0; r < 16; ++r) {
            float v = acc[r];
            v = v >= 0.f ? v : SLOPE * v;
            int row = (r & 3) + 8 * (r >> 2) + 4 * half;
            if (live) xrow[row * CH] = v;
            s += v; q += v * v;
        }
    }

    // combine the two half-lanes covering the same column
    s += __shfl_xor(s, 32);
    q += __shfl_xor(q, 32);

    __shared__ float lsum[4][32];
    __shared__ float lsq[4][32];
    if (lane < 32) { lsum[wv][col] = s; lsq[wv][col] = q; }
    __syncthreads();
    if (tid < 32) {
        float S = lsum[0][tid] + lsum[1][tid] + lsum[2][tid] + lsum[3][tid];
        atomicAdd(&stats[tid], S);
    } else if (tid < 64) {
        int cc = tid - 32;
        float Q = lsq[0][cc] + lsq[1][cc] + lsq[2][cc] + lsq[3][cc];
        atomicAdd(&stats[CH + cc], Q);
    }
}

// ---- BN normalize in place on d_out ------------------------------------
__global__ __launch_bounds__(256) void bn_apply_k(
    float* __restrict__ x,
    const float* __restrict__ stats,
    const float* __restrict__ gamma,
    const float* __restrict__ beta,
    int n)
{
    int total4 = n * (CH / 4);
    int stride = gridDim.x * blockDim.x;   // multiple of 8
    int g = blockIdx.x * blockDim.x + threadIdx.x;
    int c4 = g & 7;

    float scale[4], shift[4];
    float rn = 1.0f / (float)n;
#pragma unroll
    for (int j = 0; j < 4; ++j) {
        int oc = c4 * 4 + j;
        float m  = stats[oc] * rn;
        float v  = stats[CH + oc] * rn - m * m;
        float iv = rsqrtf(v + EPS) * gamma[oc];
        scale[j] = iv;
        shift[j] = beta[oc] - m * iv;
    }

    float4* x4 = (float4*)x;
    for (; g < total4; g += stride) {
        float4 v = x4[g];
        v.x = fmaf(v.x, scale[0], shift[0]);
        v.y = fmaf(v.y, scale[1], shift[1]);
        v.z = fmaf(v.z, scale[2], shift[2]);
        v.w = fmaf(v.w, scale[3], shift[3]);
        x4[g] = v;
    }
}

extern "C" void kernel_launch(void* const* d_in, const int* in_sizes, int n_in,
                              void* d_out, int out_size, void* d_ws, size_t ws_size,
                              hipStream_t stream)
{
    const float* features = (const float*)d_in[0];
    const int4*  coords   = (const int4*)d_in[1];
    const float* weight   = (const float*)d_in[2];
    const float* gamma    = (const float*)d_in[3];
    const float* beta     = (const float*)d_in[4];
    float* out = (float*)d_out;

    int n = in_sizes[0] / CH;            // 400000
    int ntile = (n + 31) / 32;           // 12500

    // ws layout: featb(bf16) | lookup | bfrag | stats
    unsigned short* featb = (unsigned short*)d_ws;                 // 25.6 MB
    size_t featb_bytes = (size_t)n * CH * 2;
    featb_bytes = (featb_bytes + 255) & ~(size_t)255;
    int* lookup = (int*)((char*)d_ws + featb_bytes);               // 44.2 MB
    char* after_lookup = (char*)lookup + LOOKUP_BYTES;
    short8* bfrag = (short8*)after_lookup;                         // 18 KB
    float* stats = (float*)(after_lookup + 9 * 2 * 64 * sizeof(short8));

    hipMemsetAsync(lookup, 0xFF, LOOKUP_BYTES, stream);
    hipMemsetAsync(stats, 0, 2 * CH * sizeof(float), stream);

    int blocks = (n + 255) / 256;
    scatter_convert_k<<<blocks, 256, 0, stream>>>(
        (const float4*)features, coords, lookup, featb, n);
    bfrag_prep_k<<<1, 64, 0, stream>>>(weight, bfrag);

    int conv_blocks = 1250;
    int nwaves = conv_blocks * 4;
    conv_mfma_k<<<conv_blocks, 256, 0, stream>>>(
        (const short*)featb, coords, lookup, bfrag, out, stats, n, ntile, nwaves);

    bn_apply_k<<<2048, 256, 0, stream>>>(out, stats, gamma, beta, n);
}

// Round 3
// 98.026 us; speedup vs baseline: 2.1899x; 1.1277x over previous
//
#include <hip/hip_runtime.h>
#include <hip/hip_bf16.h>

#define S0 480
#define S1 360
#define S2 32
#define CH 32
#define EPS 1e-5f
#define SLOPE 0.01f

#define LOOKUP_INTS (2 * S0 * S1 * S2)          // 11,059,200
#define LOOKUP_BYTES ((size_t)LOOKUP_INTS * 4)  // 44,236,800

typedef short short8 __attribute__((ext_vector_type(8)));
typedef float f32x16 __attribute__((ext_vector_type(16)));

__device__ __forceinline__ unsigned short f2b(float f) {
    union { __hip_bfloat16 b; unsigned short u; } v;
    v.b = __float2bfloat16(f);
    return v.u;
}

// ---- scatter lookup only -----------------------------------------------
__global__ __launch_bounds__(256) void scatter_k(
    const int4* __restrict__ coords, int* __restrict__ lookup, int n)
{
    int i = blockIdx.x * 256 + threadIdx.x;
    if (i < n) {
        int4 c = coords[i];
        int lin = ((c.x * S0 + c.y) * S1 + c.z) * S2 + c.w;
        lookup[lin] = i;
    }
}

// ---- pre-pack weights into per-lane MFMA B fragments -------------------
// B layout for mfma_f32_32x32x16_bf16: col = lane&31, k = 8*(lane>>5)+j
__global__ void bfrag_prep_k(const float* __restrict__ weight,
                             short8* __restrict__ bfrag)
{
    int lane = threadIdx.x;          // 64 threads
    int half = lane >> 5;
    int col  = lane & 31;
#pragma unroll
    for (int t = 0; t < 9; ++t)
#pragma unroll
        for (int h = 0; h < 2; ++h) {
            short8 fr;
#pragma unroll
            for (int j = 0; j < 8; ++j) {
                int ic = h * 16 + half * 8 + j;
                fr[j] = (short)f2b(weight[t * (CH * CH) + ic * CH + col]);
            }
            bfrag[(t * 2 + h) * 64 + lane] = fr;
        }
}

// ---- conv via MFMA: one wave = one tile of 32 points x 32 oc -----------
__global__ __launch_bounds__(256) void conv_mfma_k(
    const float* __restrict__ features,
    const int4*  __restrict__ coords,
    const int*   __restrict__ lookup,
    const short8* __restrict__ bfrag,
    unsigned short* __restrict__ xout,   // bf16 x, row-major [n][32]
    float*        __restrict__ stats_part, // [gridDim.x][64]
    int n, int ntile)
{
    int tid  = threadIdx.x;
    int lane = tid & 63;
    int wv   = tid >> 6;
    int half = lane >> 5;
    int col  = lane & 31;

    short8 B[9][2];
#pragma unroll
    for (int t = 0; t < 9; ++t) {
        B[t][0] = bfrag[(t * 2 + 0) * 64 + lane];
        B[t][1] = bfrag[(t * 2 + 1) * 64 + lane];
    }

    int tile = blockIdx.x * 4 + wv;
    bool tlive = (tile < ntile);
    int p  = tile * 32 + col;
    bool live = tlive && (p < n);
    int pc = live ? p : 0;

    // --- phase 1: 9 independent lookup gathers ---
    int4 c = coords[pc];
    int lin = ((c.x * S0 + c.y) * S1 + c.z) * S2 + c.w;
    int nbr[9];
#pragma unroll
    for (int d0 = 0; d0 < 3; ++d0) {
        int n0 = c.y + d0 - 1;
        bool v0 = (n0 >= 0) & (n0 < S0) & live;
#pragma unroll
        for (int d2 = 0; d2 < 3; ++d2) {
            int n2 = c.w + d2 - 1;
            bool v = v0 & (n2 >= 0) & (n2 < S2);
            nbr[d0 * 3 + d2] = v ? lookup[lin + (d0 - 1) * (S1 * S2) + (d2 - 1)] : -1;
        }
    }

    // --- phase 2: all 36 feature loads staged, converted to bf16 frags ---
    short8 A0[9], A1[9];
#pragma unroll
    for (int t = 0; t < 9; ++t) {
        int nb = nbr[t];
        if (nb >= 0) {
            const float4* fp = (const float4*)(features + (size_t)nb * CH);
            float4 x0 = fp[half * 2 + 0];
            float4 x1 = fp[half * 2 + 1];
            float4 y0 = fp[half * 2 + 4];
            float4 y1 = fp[half * 2 + 5];
            short8 a0, a1;
            a0[0] = (short)f2b(x0.x); a0[1] = (short)f2b(x0.y);
            a0[2] = (short)f2b(x0.z); a0[3] = (short)f2b(x0.w);
            a0[4] = (short)f2b(x1.x); a0[5] = (short)f2b(x1.y);
            a0[6] = (short)f2b(x1.z); a0[7] = (short)f2b(x1.w);
            a1[0] = (short)f2b(y0.x); a1[1] = (short)f2b(y0.y);
            a1[2] = (short)f2b(y0.z); a1[3] = (short)f2b(y0.w);
            a1[4] = (short)f2b(y1.x); a1[5] = (short)f2b(y1.y);
            a1[6] = (short)f2b(y1.z); a1[7] = (short)f2b(y1.w);
            A0[t] = a0; A1[t] = a1;
        } else {
            short8 z;
#pragma unroll
            for (int j = 0; j < 8; ++j) z[j] = 0;
            A0[t] = z; A1[t] = z;
        }
    }

    // --- phase 3: 18 MFMAs ---
    f32x16 acc;
#pragma unroll
    for (int r = 0; r < 16; ++r) acc[r] = 0.f;
#pragma unroll
    for (int t = 0; t < 9; ++t) {
        acc = __builtin_amdgcn_mfma_f32_32x32x16_bf16(A0[t], B[t][0], acc, 0, 0, 0);
        acc = __builtin_amdgcn_mfma_f32_32x32x16_bf16(A1[t], B[t][1], acc, 0, 0, 0);
    }

    // --- epilogue: LeakyReLU + bf16 store + stats ---
    // C/D layout: col = lane&31, row = (r&3) + 8*(r>>2) + 4*half
    float s = 0.f, q = 0.f;
#pragma unroll
    for (int r = 0; r < 16; ++r) {
        float v = acc[r];
        v = v >= 0.f ? v : SLOPE * v;
        int row = (r & 3) + 8 * (r >> 2) + 4 * half;
        if (live) {
            xout[((size_t)tile * 32 + row) * CH + col] = f2b(v);
            s += v; q += v * v;
        }
    }

    s += __shfl_xor(s, 32);
    q += __shfl_xor(q, 32);

    __shared__ float lsum[4][32];
    __shared__ float lsq[4][32];
    if (lane < 32) { lsum[wv][col] = s; lsq[wv][col] = q; }
    __syncthreads();
    if (tid < 32) {
        stats_part[(size_t)blockIdx.x * 64 + tid] =
            lsum[0][tid] + lsum[1][tid] + lsum[2][tid] + lsum[3][tid];
    } else if (tid < 64) {
        int cc = tid - 32;
        stats_part[(size_t)blockIdx.x * 64 + tid] =
            lsq[0][cc] + lsq[1][cc] + lsq[2][cc] + lsq[3][cc];
    }
}

// ---- deterministic partial reduce: 64 blocks, one stat column each -----
__global__ __launch_bounds__(256) void reduce_stats_k(
    const float* __restrict__ part, float* __restrict__ stats, int nb)
{
    int c = blockIdx.x;            // 0..63
    float s = 0.f;
    for (int i = threadIdx.x; i < nb; i += 256)
        s += part[(size_t)i * 64 + c];
#pragma unroll
    for (int m = 32; m > 0; m >>= 1) s += __shfl_xor(s, m, 64);
    __shared__ float red[4];
    int wv = threadIdx.x >> 6;
    if ((threadIdx.x & 63) == 0) red[wv] = s;
    __syncthreads();
    if (threadIdx.x == 0) stats[c] = red[0] + red[1] + red[2] + red[3];
}

// ---- BN normalize: bf16 x -> fp32 out ----------------------------------
__global__ __launch_bounds__(256) void bn_apply_k(
    const unsigned short* __restrict__ xb,
    const float* __restrict__ stats,
    const float* __restrict__ gamma,
    const float* __restrict__ beta,
    float* __restrict__ out,
    int n)
{
    int total8 = n * 4;                       // groups of 8 elems
    int stride = gridDim.x * blockDim.x;      // multiple of 4
    int g = blockIdx.x * blockDim.x + threadIdx.x;
    int c8 = g & 3;                           // which 8-channel slot

    float scale[8], shift[8];
    float rn = 1.0f / (float)n;
#pragma unroll
    for (int j = 0; j < 8; ++j) {
        int oc = c8 * 8 + j;
        float m  = stats[oc] * rn;
        float vv = stats[CH + oc] * rn - m * m;
        float iv = rsqrtf(vv + EPS) * gamma[oc];
        scale[j] = iv;
        shift[j] = beta[oc] - m * iv;
    }

    const short8* x8 = (const short8*)xb;
    float4* o4 = (float4*)out;
    for (; g < total8; g += stride) {
        short8 v = x8[g];
        float f[8];
#pragma unroll
        for (int j = 0; j < 8; ++j) {
            unsigned int u = ((unsigned int)(unsigned short)v[j]) << 16;
            union { unsigned int u; float f; } w; w.u = u;
            f[j] = fmaf(w.f, scale[j], shift[j]);
        }
        o4[g * 2 + 0] = make_float4(f[0], f[1], f[2], f[3]);
        o4[g * 2 + 1] = make_float4(f[4], f[5], f[6], f[7]);
    }
}

extern "C" void kernel_launch(void* const* d_in, const int* in_sizes, int n_in,
                              void* d_out, int out_size, void* d_ws, size_t ws_size,
                              hipStream_t stream)
{
    const float* features = (const float*)d_in[0];
    const int4*  coords   = (const int4*)d_in[1];
    const float* weight   = (const float*)d_in[2];
    const float* gamma    = (const float*)d_in[3];
    const float* beta     = (const float*)d_in[4];
    float* out = (float*)d_out;

    int n = in_sizes[0] / CH;            // 400000
    int ntile = (n + 31) / 32;           // 12500
    int conv_blocks = (ntile + 3) / 4;   // 3125

    // ws layout: lookup | xout(bf16) | stats_part | bfrag | stats
    int* lookup = (int*)d_ws;
    size_t off = LOOKUP_BYTES;                                   // 44,236,800
    unsigned short* xout = (unsigned short*)((char*)d_ws + off);
    off += (size_t)ntile * 32 * CH * 2;                          // 25,600,000
    float* stats_part = (float*)((char*)d_ws + off);
    off += (size_t)conv_blocks * 64 * sizeof(float);             // 800,000
    short8* bfrag = (short8*)((char*)d_ws + off);
    off += 9 * 2 * 64 * sizeof(short8);                          // 18,432
    float* stats = (float*)((char*)d_ws + off);

    hipMemsetAsync(lookup, 0xFF, LOOKUP_BYTES, stream);

    scatter_k<<<(n + 255) / 256, 256, 0, stream>>>(coords, lookup, n);
    bfrag_prep_k<<<1, 64, 0, stream>>>(weight, bfrag);

    conv_mfma_k<<<conv_blocks, 256, 0, stream>>>(
        features, coords, lookup, bfrag, xout, stats_part, n, ntile);

    reduce_stats_k<<<64, 256, 0, stream>>>(stats_part, stats, conv_blocks);

    bn_apply_k<<<2048, 256, 0, stream>>>(xout, stats, gamma, beta, out, n);
}